// Round 4
// baseline (3005.795 us; speedup 1.0000x reference)
//
#include <hip/hip_runtime.h>

#define NN 50000
#define NE 1600000
#define DD 64
#define NBK 782     // ceil(NN/64) buckets of 64 dst nodes
#define TILE 8192   // edges per binning block
#define NTB 196     // ceil(NE/TILE)

// out = x*temp[0]; xbuf = x
__global__ __launch_bounds__(256) void init_kernel(const float4* __restrict__ x,
                                                   float4* __restrict__ out,
                                                   float4* __restrict__ xbuf,
                                                   const float* __restrict__ temp) {
    int i = blockIdx.x * blockDim.x + threadIdx.x;
    const int n4 = NN * DD / 4;
    if (i < n4) {
        float t0 = temp[0];
        float4 v = x[i];
        xbuf[i] = v;
        float4 o;
        o.x = v.x * t0; o.y = v.y * t0; o.z = v.z * t0; o.w = v.w * t0;
        out[i] = o;
    }
}

// per-block LDS bucket histogram -> global bucket counts
__global__ __launch_bounds__(256) void binA_count(const int* __restrict__ dst,
                                                  int* __restrict__ gcnt) {
    __shared__ int cnt[NBK];
    int t = threadIdx.x;
    for (int k = t; k < NBK; k += 256) cnt[k] = 0;
    __syncthreads();
    int base = blockIdx.x * TILE;
#pragma unroll
    for (int k = 0; k < TILE / 256; ++k) {
        int i = base + k * 256 + t;
        if (i < NE) atomicAdd(&cnt[dst[i] >> 6], 1);
    }
    __syncthreads();
    for (int k = t; k < NBK; k += 256)
        if (cnt[k]) atomicAdd(&gcnt[k], cnt[k]);
}

// exclusive scan of bucket counts; init gcur = gbase
__global__ __launch_bounds__(1024) void scan_kernel(const int* __restrict__ gcnt,
                                                    int* __restrict__ gbase,
                                                    int* __restrict__ gcur) {
    __shared__ int sd[1024];
    int t = threadIdx.x;
    int v = (t < NBK) ? gcnt[t] : 0;
    sd[t] = v;
    __syncthreads();
    for (int s = 1; s < 1024; s <<= 1) {
        int add = (t >= s) ? sd[t - s] : 0;
        __syncthreads();
        sd[t] += add;
        __syncthreads();
    }
    if (t < NBK) { int ex = sd[t] - v; gbase[t] = ex; gcur[t] = ex; }
    if (t == 0) gbase[NBK] = NE;
}

// bin edges into bucket-contiguous regions; per-block contiguous bursts per bucket
__global__ __launch_bounds__(256) void binA_fill(const int* __restrict__ src,
                                                 const int* __restrict__ dst,
                                                 const float* __restrict__ w,
                                                 int* __restrict__ gcur,
                                                 int2* __restrict__ csr) {
    __shared__ int cnt[NBK];
    __shared__ int bas[NBK];
    __shared__ int rnk[NBK];
    int t = threadIdx.x;
    for (int k = t; k < NBK; k += 256) { cnt[k] = 0; rnk[k] = 0; }
    __syncthreads();
    int base = blockIdx.x * TILE;
#pragma unroll
    for (int k = 0; k < TILE / 256; ++k) {
        int i = base + k * 256 + t;
        if (i < NE) atomicAdd(&cnt[dst[i] >> 6], 1);
    }
    __syncthreads();
    for (int k = t; k < NBK; k += 256) {
        int c = cnt[k];
        bas[k] = c ? atomicAdd(&gcur[k], c) : 0;
    }
    __syncthreads();
#pragma unroll
    for (int k = 0; k < TILE / 256; ++k) {
        int i = base + k * 256 + t;
        if (i < NE) {
            int d = dst[i];
            int bkt = d >> 6;
            int r = atomicAdd(&rnk[bkt], 1);
            int2 e;
            e.x = ((d & 63) << 16) | src[i];   // src < 65536
            e.y = __float_as_int(w[i]);
            csr[bas[bkt] + r] = e;
        }
    }
}

// h = x @ W^T + b ; 32 nodes/block, wave per node
__global__ __launch_bounds__(256) void gemm_kernel(const float* __restrict__ x,
                                                   const float* __restrict__ Wl,
                                                   const float* __restrict__ bl,
                                                   float* __restrict__ h) {
    __shared__ float WT[64 * 65];   // WT[d*65+o] = W[o*64+d]
    __shared__ float bs[64];
    int t = threadIdx.x;
#pragma unroll
    for (int k = 0; k < 16; ++k) {
        int idx = t + k * 256;
        int o = idx >> 6, d = idx & 63;
        WT[d * 65 + o] = Wl[o * 64 + d];
    }
    if (t < 64) bs[t] = bl[t];
    __syncthreads();
    int o = t & 63;
    int r = t >> 6;
#pragma unroll
    for (int p = 0; p < 8; ++p) {
        int node = blockIdx.x * 32 + p * 4 + r;
        if (node < NN) {
            const float* xr = x + (size_t)node * 64;
            float acc = bs[o];
#pragma unroll
            for (int d = 0; d < 64; ++d)
                acc += xr[d] * WT[d * 65 + o];   // xr[d] wave-uniform -> broadcast
            h[(size_t)node * 64 + o] = acc;
        }
    }
}

// block = one bucket (64 dst nodes). LDS float accumulator, quarter-wave float4
// gather, ds_add_f32 accumulation; fused relu + epilogue (coalesced).
__global__ __launch_bounds__(256) void pull_lds(const float4* __restrict__ h4,
                                                const int2* __restrict__ csr,
                                                const int* __restrict__ gbase,
                                                float4* __restrict__ xbuf,
                                                float4* __restrict__ out,
                                                const float* __restrict__ temp,
                                                int layer) {
    __shared__ float acc[64 * 64];   // 16 KB
    int t = threadIdx.x;
    int bkt = blockIdx.x;
#pragma unroll
    for (int k = 0; k < 16; ++k) acc[t + k * 256] = 0.f;
    __syncthreads();

    int ebeg = gbase[bkt], eend = gbase[bkt + 1];
    int lane = t & 63;
    int wv = t >> 6;
    int q = lane >> 4, sub = lane & 15;

    for (int base = ebeg + wv * 64; base < eend; base += 256) {
        int cnt = eend - base;
        if (cnt > 64) cnt = 64;
        int sp = 0; float wgt = 0.f;
        if (lane < cnt) {
            int2 e = csr[base + lane];
            sp = e.x;
            wgt = __int_as_float(e.y);
        }
        int cntp = (cnt + 3) & ~3;
        for (int j = 0; j < cntp; j += 4) {
            int ls = j + q;
            int   spj = __shfl(sp, ls);
            float wj  = __shfl(wgt, ls);       // lanes >= cnt carry w=0 -> no-op
            int s  = spj & 0xffff;
            int dl = (spj >> 16) & 0xffff;
            float4 hv = h4[(size_t)s * 16 + sub];
            float* ap = &acc[dl * 64 + sub * 4];
            atomicAdd(ap + 0, wj * hv.x);
            atomicAdd(ap + 1, wj * hv.y);
            atomicAdd(ap + 2, wj * hv.z);
            atomicAdd(ap + 3, wj * hv.w);
        }
    }
    __syncthreads();

    // epilogue: 64 nodes x 16 float4 = 1024 float4, 256 threads x 4 each
    float tk = temp[layer + 1];
    int node0 = bkt * 64;
#pragma unroll
    for (int k = 0; k < 4; ++k) {
        int idx = t + k * 256;
        int nloc = idx >> 4, sub2 = idx & 15;
        int node = node0 + nloc;
        if (node < NN) {
            float* ap = &acc[nloc * 64 + sub2 * 4];
            float4 v;
            v.x = fmaxf(ap[0], 0.f); v.y = fmaxf(ap[1], 0.f);
            v.z = fmaxf(ap[2], 0.f); v.w = fmaxf(ap[3], 0.f);
            int gi = node * 16 + sub2;
            xbuf[gi] = v;
            float4 o = out[gi];
            o.x += v.x * tk; o.y += v.y * tk;
            o.z += v.z * tk; o.w += v.w * tk;
            out[gi] = o;
        }
    }
}

extern "C" void kernel_launch(void* const* d_in, const int* in_sizes, int n_in,
                              void* d_out, int out_size, void* d_ws, size_t ws_size,
                              hipStream_t stream) {
    const float* x    = (const float*)d_in[0];
    const float* w    = (const float*)d_in[1];
    const float* W    = (const float*)d_in[2];
    const float* b    = (const float*)d_in[3];
    const float* temp = (const float*)d_in[4];
    const int*   src  = (const int*)d_in[5];
    const int*   dst  = (const int*)d_in[6];
    float* out = (float*)d_out;

    // workspace layout
    float* xbuf  = (float*)d_ws;                     // NN*DD
    float* hbuf  = xbuf + (size_t)NN * DD;           // NN*DD
    int2*  csr   = (int2*)(hbuf + (size_t)NN * DD);  // NE int2
    int*   gcnt  = (int*)(csr + NE);                 // NBK
    int*   gbase = gcnt + NBK;                       // NBK+1
    int*   gcur  = gbase + NBK + 1;                  // NBK

    // ---- bucket binning ----
    hipMemsetAsync(gcnt, 0, (size_t)NBK * sizeof(int), stream);
    binA_count<<<NTB, 256, 0, stream>>>(dst, gcnt);
    scan_kernel<<<1, 1024, 0, stream>>>(gcnt, gbase, gcur);
    binA_fill<<<NTB, 256, 0, stream>>>(src, dst, w, gcur, csr);

    // ---- init ----
    const int n4 = NN * DD / 4;
    init_kernel<<<(n4 + 255) / 256, 256, 0, stream>>>(
        (const float4*)x, (float4*)out, (float4*)xbuf, temp);

    // ---- layers ----
    for (int l = 0; l < 4; ++l) {
        gemm_kernel<<<(NN + 31) / 32, 256, 0, stream>>>(
            xbuf, W + (size_t)l * DD * DD, b + (size_t)l * DD, hbuf);
        pull_lds<<<NBK, 256, 0, stream>>>(
            (const float4*)hbuf, csr, gbase, (float4*)xbuf, (float4*)out, temp, l);
    }
}

// Round 5
// 535.140 us; speedup vs baseline: 5.6168x; 5.6168x over previous
//
#include <hip/hip_runtime.h>
#include <hip/hip_fp16.h>

#define NN 50000
#define NE 1600000
#define DD 64
#define NB_SCAN 196   // ceil(NN/256)

// out = x*temp[0]; xbuf = x
__global__ __launch_bounds__(256) void init_kernel(const float4* __restrict__ x,
                                                   float4* __restrict__ out,
                                                   float4* __restrict__ xbuf,
                                                   const float* __restrict__ temp) {
    int i = blockIdx.x * blockDim.x + threadIdx.x;
    const int n4 = NN * DD / 4;
    if (i < n4) {
        float t0 = temp[0];
        float4 v = x[i];
        xbuf[i] = v;
        float4 o;
        o.x = v.x * t0; o.y = v.y * t0; o.z = v.z * t0; o.w = v.w * t0;
        out[i] = o;
    }
}

// deg[dst[e]]++
__global__ __launch_bounds__(256) void hist_kernel(const int* __restrict__ dst,
                                                   int* __restrict__ deg) {
    int i = blockIdx.x * blockDim.x + threadIdx.x;
    if (i < NE) atomicAdd(&deg[dst[i]], 1);
}

__global__ __launch_bounds__(256) void blocksum_kernel(const int* __restrict__ deg,
                                                       int* __restrict__ bsum) {
    __shared__ int sd[256];
    int t = threadIdx.x;
    int i = blockIdx.x * 256 + t;
    sd[t] = (i < NN) ? deg[i] : 0;
    __syncthreads();
    for (int s = 128; s > 0; s >>= 1) {
        if (t < s) sd[t] += sd[t + s];
        __syncthreads();
    }
    if (t == 0) bsum[blockIdx.x] = sd[0];
}

__global__ __launch_bounds__(256) void scantops_kernel(const int* __restrict__ bsum,
                                                       int* __restrict__ boff) {
    __shared__ int sd[256];
    int t = threadIdx.x;
    int v = (t < NB_SCAN) ? bsum[t] : 0;
    sd[t] = v;
    __syncthreads();
    for (int s = 1; s < 256; s <<= 1) {
        int add = (t >= s) ? sd[t - s] : 0;
        __syncthreads();
        sd[t] += add;
        __syncthreads();
    }
    boff[t] = sd[t] - v;   // exclusive
}

__global__ __launch_bounds__(256) void scanfinal_kernel(const int* __restrict__ deg,
                                                        const int* __restrict__ boff,
                                                        int* __restrict__ off) {
    __shared__ int sd[256];
    int t = threadIdx.x;
    int i = blockIdx.x * 256 + t;
    int v = (i < NN) ? deg[i] : 0;
    sd[t] = v;
    __syncthreads();
    for (int s = 1; s < 256; s <<= 1) {
        int add = (t >= s) ? sd[t - s] : 0;
        __syncthreads();
        sd[t] += add;
        __syncthreads();
    }
    if (i < NN) off[i] = boff[blockIdx.x] + sd[t] - v;
    if (blockIdx.x == 0 && t == 0) off[NN] = NE;
}

// bucket edges by dst; 4B packed entry: src (16b) | w_fp16 (16b)
__global__ __launch_bounds__(256) void fill_kernel(const int* __restrict__ src,
                                                   const int* __restrict__ dst,
                                                   const float* __restrict__ w,
                                                   int* __restrict__ cur,
                                                   unsigned int* __restrict__ csr) {
    int i = blockIdx.x * blockDim.x + threadIdx.x;
    if (i < NE) {
        int d = dst[i];
        int pos = atomicAdd(&cur[d], 1);
        unsigned int wh = (unsigned int)__half_as_ushort(__float2half_rn(w[i]));
        csr[pos] = (unsigned int)src[i] | (wh << 16);
    }
}

// h = x @ W^T + b, h stored fp16 ; 32 nodes/block, wave per node
__global__ __launch_bounds__(256) void gemm_kernel(const float* __restrict__ x,
                                                   const float* __restrict__ Wl,
                                                   const float* __restrict__ bl,
                                                   __half* __restrict__ h) {
    __shared__ float WT[64 * 65];   // WT[d*65+o] = W[o*64+d]
    __shared__ float bs[64];
    int t = threadIdx.x;
#pragma unroll
    for (int k = 0; k < 16; ++k) {
        int idx = t + k * 256;
        int o = idx >> 6, d = idx & 63;
        WT[d * 65 + o] = Wl[o * 64 + d];
    }
    if (t < 64) bs[t] = bl[t];
    __syncthreads();
    int o = t & 63;
    int r = t >> 6;
#pragma unroll
    for (int p = 0; p < 8; ++p) {
        int node = blockIdx.x * 32 + p * 4 + r;
        if (node < NN) {
            const float* xr = x + (size_t)node * 64;
            float acc = bs[o];
#pragma unroll
            for (int d = 0; d < 64; ++d)
                acc += xr[d] * WT[d * 65 + o];   // xr[d] wave-uniform -> broadcast
            h[(size_t)node * 64 + o] = __float2half_rn(acc);
        }
    }
}

// pull, eighth-wave fp16: wave = 1 node; lane = (oct=lane>>3, sub=lane&7).
// Each oct processes a different edge; each lane holds 8 fp16 features (uint4).
__global__ __launch_bounds__(256) void pull_kernel(const uint4* __restrict__ h16,
                                                   const unsigned int* __restrict__ csr,
                                                   const int* __restrict__ off,
                                                   float4* __restrict__ xbuf,
                                                   float4* __restrict__ out,
                                                   const float* __restrict__ temp,
                                                   int layer) {
    int node = blockIdx.x * 4 + (threadIdx.x >> 6);
    int lane = threadIdx.x & 63;
    if (node >= NN) return;
    int oct = lane >> 3, sub = lane & 7;
    int beg = off[node];
    int end = off[node + 1];
    float acc[8];
#pragma unroll
    for (int k = 0; k < 8; ++k) acc[k] = 0.f;

    for (int base = beg; base < end; base += 64) {
        int cnt = end - base;
        if (cnt > 64) cnt = 64;
        unsigned int e = 0;                    // src=0, w=+0 -> no-op for idle lanes
        if (lane < cnt) e = csr[base + lane];
        int cntp = (cnt + 7) & ~7;
        for (int j = 0; j < cntp; j += 8) {
            unsigned int ej = (unsigned int)__shfl((int)e, j + oct);
            int   s  = (int)(ej & 0xffffu);
            float wj = __half2float(__ushort_as_half((unsigned short)(ej >> 16)));
            uint4 hv = h16[(size_t)s * 8 + sub];
            const __half2* hp = (const __half2*)&hv;
#pragma unroll
            for (int k = 0; k < 4; ++k) {
                float2 f = __half22float2(hp[k]);
                acc[2 * k]     += wj * f.x;
                acc[2 * k + 1] += wj * f.y;
            }
        }
    }
    // reduce partial sums across the 8 octs
#pragma unroll
    for (int m = 8; m < 64; m <<= 1) {
#pragma unroll
        for (int k = 0; k < 8; ++k) acc[k] += __shfl_xor(acc[k], m);
    }
    if (oct == 0) {
        float tk = temp[layer + 1];
        float4 v0, v1;
        v0.x = fmaxf(acc[0], 0.f); v0.y = fmaxf(acc[1], 0.f);
        v0.z = fmaxf(acc[2], 0.f); v0.w = fmaxf(acc[3], 0.f);
        v1.x = fmaxf(acc[4], 0.f); v1.y = fmaxf(acc[5], 0.f);
        v1.z = fmaxf(acc[6], 0.f); v1.w = fmaxf(acc[7], 0.f);
        int gi = node * 16 + sub * 2;
        xbuf[gi]     = v0;
        xbuf[gi + 1] = v1;
        float4 o0 = out[gi], o1 = out[gi + 1];
        o0.x += v0.x * tk; o0.y += v0.y * tk; o0.z += v0.z * tk; o0.w += v0.w * tk;
        o1.x += v1.x * tk; o1.y += v1.y * tk; o1.z += v1.z * tk; o1.w += v1.w * tk;
        out[gi]     = o0;
        out[gi + 1] = o1;
    }
}

extern "C" void kernel_launch(void* const* d_in, const int* in_sizes, int n_in,
                              void* d_out, int out_size, void* d_ws, size_t ws_size,
                              hipStream_t stream) {
    const float* x    = (const float*)d_in[0];
    const float* w    = (const float*)d_in[1];
    const float* W    = (const float*)d_in[2];
    const float* b    = (const float*)d_in[3];
    const float* temp = (const float*)d_in[4];
    const int*   src  = (const int*)d_in[5];
    const int*   dst  = (const int*)d_in[6];
    float* out = (float*)d_out;

    // workspace layout (~26 MB)
    float*        xbuf = (float*)d_ws;                        // NN*DD f32
    __half*       hbuf = (__half*)(xbuf + (size_t)NN * DD);   // NN*DD f16
    unsigned int* csr  = (unsigned int*)(hbuf + (size_t)NN * DD); // NE u32
    int*          deg  = (int*)(csr + NE);                    // NN
    int*          off  = deg + NN;                            // NN+1
    int*          cur  = off + NN + 1;                        // NN+1
    int*          bsum = cur + NN + 1;                        // 256
    int*          boff = bsum + 256;                          // 256

    // ---- CSR build ----
    hipMemsetAsync(deg, 0, (size_t)NN * sizeof(int), stream);
    hist_kernel<<<(NE + 255) / 256, 256, 0, stream>>>(dst, deg);
    blocksum_kernel<<<NB_SCAN, 256, 0, stream>>>(deg, bsum);
    scantops_kernel<<<1, 256, 0, stream>>>(bsum, boff);
    scanfinal_kernel<<<NB_SCAN, 256, 0, stream>>>(deg, boff, off);
    hipMemcpyAsync(cur, off, (size_t)(NN + 1) * sizeof(int),
                   hipMemcpyDeviceToDevice, stream);
    fill_kernel<<<(NE + 255) / 256, 256, 0, stream>>>(src, dst, w, cur, csr);

    // ---- init ----
    const int n4 = NN * DD / 4;
    init_kernel<<<(n4 + 255) / 256, 256, 0, stream>>>(
        (const float4*)x, (float4*)out, (float4*)xbuf, temp);

    // ---- layers ----
    for (int l = 0; l < 4; ++l) {
        gemm_kernel<<<(NN + 31) / 32, 256, 0, stream>>>(
            xbuf, W + (size_t)l * DD * DD, b + (size_t)l * DD, hbuf);
        pull_kernel<<<(NN + 3) / 4, 256, 0, stream>>>(
            (const uint4*)hbuf, csr, off, (float4*)xbuf, (float4*)out, temp, l);
    }
}

// Round 6
// 398.345 us; speedup vs baseline: 7.5457x; 1.3434x over previous
//
#include <hip/hip_runtime.h>
#include <hip/hip_fp16.h>

#define NN 50000
#define NE 1600000
#define DD 64
#define NBK 782      // ceil(NN/64) buckets of 64 dst nodes
#define TILE 4096    // edges per binning block
#define NTB 391      // ceil(NE/TILE)
#define SCAP 3072    // per-bucket capacity (mean 2048, sigma ~45)

// out = x*temp[0]; xbuf = x
__global__ __launch_bounds__(256) void init_kernel(const float4* __restrict__ x,
                                                   float4* __restrict__ out,
                                                   float4* __restrict__ xbuf,
                                                   const float* __restrict__ temp) {
    int i = blockIdx.x * blockDim.x + threadIdx.x;
    const int n4 = NN * DD / 4;
    if (i < n4) {
        float t0 = temp[0];
        float4 v = x[i];
        xbuf[i] = v;
        float4 o;
        o.x = v.x * t0; o.y = v.y * t0; o.z = v.z * t0; o.w = v.w * t0;
        out[i] = o;
    }
}

// per-block LDS bucket histogram -> global bucket counts
__global__ __launch_bounds__(256) void count_kernel(const int* __restrict__ dst,
                                                    int* __restrict__ gcnt) {
    __shared__ int cnt[NBK];
    int t = threadIdx.x;
    for (int k = t; k < NBK; k += 256) cnt[k] = 0;
    __syncthreads();
    int base = blockIdx.x * TILE;
#pragma unroll
    for (int k = 0; k < TILE / 256; ++k) {
        int i = base + k * 256 + t;
        if (i < NE) atomicAdd(&cnt[dst[i] >> 6], 1);
    }
    __syncthreads();
    for (int k = t; k < NBK; k += 256)
        if (cnt[k]) atomicAdd(&gcnt[k], cnt[k]);
}

// exclusive scan of the NBK bucket counts
__global__ __launch_bounds__(1024) void scan_kernel(const int* __restrict__ gcnt,
                                                    int* __restrict__ gbase) {
    __shared__ int sd[1024];
    int t = threadIdx.x;
    int v = (t < NBK) ? gcnt[t] : 0;
    sd[t] = v;
    __syncthreads();
    for (int s = 1; s < 1024; s <<= 1) {
        int add = (t >= s) ? sd[t - s] : 0;
        __syncthreads();
        sd[t] += add;
        __syncthreads();
    }
    if (t < NBK) gbase[t] = sd[t] - v;
    if (t == 0) gbase[NBK] = NE;
}

// tile -> LDS reorder by bucket -> burst write to reserved per-(block,bucket)
// contiguous segments. Entry: x = src | dst<<16 (both <65536), y = w bits.
__global__ __launch_bounds__(256) void fill_kernel(const int* __restrict__ src,
                                                   const int* __restrict__ dst,
                                                   const float* __restrict__ w,
                                                   const int* __restrict__ gbase,
                                                   int* __restrict__ gcur,
                                                   uint2* __restrict__ tmp) {
    __shared__ uint2 data[TILE];        // 32 KB
    __shared__ int cnt[NBK], bas[NBK], rnk[NBK];
    __shared__ int sc[1024];
    int t = threadIdx.x;
    for (int k = t; k < NBK; k += 256) { cnt[k] = 0; rnk[k] = 0; }
    __syncthreads();
    int base = blockIdx.x * TILE;
    uint2 er[TILE / 256];
#pragma unroll
    for (int k = 0; k < TILE / 256; ++k) {
        int i = base + k * 256 + t;
        if (i < NE) {
            uint2 e;
            e.x = (unsigned int)src[i] | ((unsigned int)dst[i] << 16);
            e.y = (unsigned int)__float_as_int(w[i]);
            er[k] = e;
            atomicAdd(&cnt[e.x >> 22], 1);   // bucket = dst>>6
        }
    }
    __syncthreads();
    // reserve global space per bucket
    for (int k = t; k < NBK; k += 256) {
        int c = cnt[k];
        bas[k] = c ? atomicAdd(&gcur[k], c) : 0;
    }
    // local exclusive scan of cnt (Hillis-Steele over 1024 slots)
    for (int k = t; k < 1024; k += 256) sc[k] = (k < NBK) ? cnt[k] : 0;
    __syncthreads();
    for (int s = 1; s < 1024; s <<= 1) {
        int v0[4];
#pragma unroll
        for (int j = 0; j < 4; ++j) {
            int idx = t + j * 256;
            v0[j] = (idx >= s) ? sc[idx - s] : 0;
        }
        __syncthreads();
#pragma unroll
        for (int j = 0; j < 4; ++j) sc[t + j * 256] += v0[j];
        __syncthreads();
    }
    // place entries bucket-contiguously in LDS
#pragma unroll
    for (int k = 0; k < TILE / 256; ++k) {
        int i = base + k * 256 + t;
        if (i < NE) {
            uint2 e = er[k];
            int b = e.x >> 22;
            int r = atomicAdd(&rnk[b], 1);
            data[(sc[b] - cnt[b]) + r] = e;
        }
    }
    __syncthreads();
    // sequential write-out: same-line stores are temporally adjacent
    int tot = NE - base; if (tot > TILE) tot = TILE;
    for (int idx = t; idx < tot; idx += 256) {
        uint2 e = data[idx];
        int b = e.x >> 22;
        int lb = sc[b] - cnt[b];
        tmp[gbase[b] + bas[b] + (idx - lb)] = e;
    }
}

// block = bucket: LDS counting-sort by dst-local, emit packed 4B CSR + off[]
__global__ __launch_bounds__(256) void sort_kernel(const uint2* __restrict__ tmp,
                                                   const int* __restrict__ gbase,
                                                   unsigned int* __restrict__ csr,
                                                   int* __restrict__ off) {
    __shared__ unsigned int pk[SCAP];
    __shared__ unsigned char dl[SCAP];
    __shared__ unsigned int outp[SCAP];
    __shared__ int cnt[64], nb[64], pos[64];
    int b = blockIdx.x, t = threadIdx.x;
    int beg = gbase[b], n = gbase[b + 1] - beg;
    if (t < 64) cnt[t] = 0;
    __syncthreads();
    for (int i = t; i < n; i += 256) {
        uint2 e = tmp[beg + i];
        unsigned int s = e.x & 0xffffu;
        unsigned int d = (e.x >> 16) & 63u;
        unsigned int wh = (unsigned int)__half_as_ushort(
            __float2half_rn(__int_as_float((int)e.y)));
        pk[i] = s | (wh << 16);
        dl[i] = (unsigned char)d;
        atomicAdd(&cnt[(int)d], 1);
    }
    __syncthreads();
    if (t == 0) {
        int a = 0;
        for (int k = 0; k < 64; ++k) { nb[k] = a; pos[k] = a; a += cnt[k]; }
    }
    __syncthreads();
    for (int i = t; i < n; i += 256) {
        int d = dl[i];
        int r = atomicAdd(&pos[d], 1);
        outp[r] = pk[i];
    }
    __syncthreads();
    for (int i = t; i < n; i += 256) csr[beg + i] = outp[i];
    if (t < 64) {
        int node = b * 64 + t;
        if (node < NN) off[node] = beg + nb[t];
    }
    if (b == NBK - 1 && t == 0) off[NN] = NE;
}

// h = x @ W^T + b, h stored fp16 ; 32 nodes/block, wave per node
__global__ __launch_bounds__(256) void gemm_kernel(const float* __restrict__ x,
                                                   const float* __restrict__ Wl,
                                                   const float* __restrict__ bl,
                                                   __half* __restrict__ h) {
    __shared__ float WT[64 * 65];   // WT[d*65+o] = W[o*64+d]
    __shared__ float bs[64];
    int t = threadIdx.x;
#pragma unroll
    for (int k = 0; k < 16; ++k) {
        int idx = t + k * 256;
        int o = idx >> 6, d = idx & 63;
        WT[d * 65 + o] = Wl[o * 64 + d];
    }
    if (t < 64) bs[t] = bl[t];
    __syncthreads();
    int o = t & 63;
    int r = t >> 6;
#pragma unroll
    for (int p = 0; p < 8; ++p) {
        int node = blockIdx.x * 32 + p * 4 + r;
        if (node < NN) {
            const float* xr = x + (size_t)node * 64;
            float acc = bs[o];
#pragma unroll
            for (int d = 0; d < 64; ++d)
                acc += xr[d] * WT[d * 65 + o];   // xr[d] wave-uniform -> broadcast
            h[(size_t)node * 64 + o] = __float2half_rn(acc);
        }
    }
}

// pull, eighth-wave fp16: wave = 1 node; lane = (oct=lane>>3, sub=lane&7).
__global__ __launch_bounds__(256) void pull_kernel(const uint4* __restrict__ h16,
                                                   const unsigned int* __restrict__ csr,
                                                   const int* __restrict__ off,
                                                   float4* __restrict__ xbuf,
                                                   float4* __restrict__ out,
                                                   const float* __restrict__ temp,
                                                   int layer) {
    int node = blockIdx.x * 4 + (threadIdx.x >> 6);
    int lane = threadIdx.x & 63;
    if (node >= NN) return;
    int oct = lane >> 3, sub = lane & 7;
    int beg = off[node];
    int end = off[node + 1];
    float acc[8];
#pragma unroll
    for (int k = 0; k < 8; ++k) acc[k] = 0.f;

    for (int base = beg; base < end; base += 64) {
        int cnt = end - base;
        if (cnt > 64) cnt = 64;
        unsigned int e = 0;                    // src=0, w=+0 -> no-op for idle lanes
        if (lane < cnt) e = csr[base + lane];
        int cntp = (cnt + 7) & ~7;
        for (int j = 0; j < cntp; j += 8) {
            unsigned int ej = (unsigned int)__shfl((int)e, j + oct);
            int   s  = (int)(ej & 0xffffu);
            float wj = __half2float(__ushort_as_half((unsigned short)(ej >> 16)));
            uint4 hv = h16[(size_t)s * 8 + sub];
            const __half2* hp = (const __half2*)&hv;
#pragma unroll
            for (int k = 0; k < 4; ++k) {
                float2 f = __half22float2(hp[k]);
                acc[2 * k]     += wj * f.x;
                acc[2 * k + 1] += wj * f.y;
            }
        }
    }
#pragma unroll
    for (int m = 8; m < 64; m <<= 1) {
#pragma unroll
        for (int k = 0; k < 8; ++k) acc[k] += __shfl_xor(acc[k], m);
    }
    if (oct == 0) {
        float tk = temp[layer + 1];
        float4 v0, v1;
        v0.x = fmaxf(acc[0], 0.f); v0.y = fmaxf(acc[1], 0.f);
        v0.z = fmaxf(acc[2], 0.f); v0.w = fmaxf(acc[3], 0.f);
        v1.x = fmaxf(acc[4], 0.f); v1.y = fmaxf(acc[5], 0.f);
        v1.z = fmaxf(acc[6], 0.f); v1.w = fmaxf(acc[7], 0.f);
        int gi = node * 16 + sub * 2;
        xbuf[gi]     = v0;
        xbuf[gi + 1] = v1;
        float4 o0 = out[gi], o1 = out[gi + 1];
        o0.x += v0.x * tk; o0.y += v0.y * tk; o0.z += v0.z * tk; o0.w += v0.w * tk;
        o1.x += v1.x * tk; o1.y += v1.y * tk; o1.z += v1.z * tk; o1.w += v1.w * tk;
        out[gi]     = o0;
        out[gi + 1] = o1;
    }
}

extern "C" void kernel_launch(void* const* d_in, const int* in_sizes, int n_in,
                              void* d_out, int out_size, void* d_ws, size_t ws_size,
                              hipStream_t stream) {
    const float* x    = (const float*)d_in[0];
    const float* w    = (const float*)d_in[1];
    const float* W    = (const float*)d_in[2];
    const float* b    = (const float*)d_in[3];
    const float* temp = (const float*)d_in[4];
    const int*   src  = (const int*)d_in[5];
    const int*   dst  = (const int*)d_in[6];
    float* out = (float*)d_out;

    // workspace layout (~39 MB)
    float*        xbuf  = (float*)d_ws;                          // NN*DD f32
    __half*       hbuf  = (__half*)(xbuf + (size_t)NN * DD);     // NN*DD f16
    unsigned int* csr   = (unsigned int*)(hbuf + (size_t)NN * DD); // NE u32
    uint2*        tmp   = (uint2*)(csr + NE);                    // NE uint2
    int*          gcnt  = (int*)(tmp + NE);                      // NBK
    int*          gbase = gcnt + NBK;                            // NBK+1
    int*          gcur  = gbase + NBK + 1;                       // NBK
    int*          off   = gcur + NBK;                            // NN+1

    // ---- CSR build ----
    hipMemsetAsync(gcnt, 0, (size_t)NBK * sizeof(int), stream);
    hipMemsetAsync(gcur, 0, (size_t)NBK * sizeof(int), stream);
    count_kernel<<<NTB, 256, 0, stream>>>(dst, gcnt);
    scan_kernel<<<1, 1024, 0, stream>>>(gcnt, gbase);
    fill_kernel<<<NTB, 256, 0, stream>>>(src, dst, w, gbase, gcur, tmp);
    sort_kernel<<<NBK, 256, 0, stream>>>(tmp, gbase, csr, off);

    // ---- init ----
    const int n4 = NN * DD / 4;
    init_kernel<<<(n4 + 255) / 256, 256, 0, stream>>>(
        (const float4*)x, (float4*)out, (float4*)xbuf, temp);

    // ---- layers ----
    for (int l = 0; l < 4; ++l) {
        gemm_kernel<<<(NN + 31) / 32, 256, 0, stream>>>(
            xbuf, W + (size_t)l * DD * DD, b + (size_t)l * DD, hbuf);
        pull_kernel<<<(NN + 3) / 4, 256, 0, stream>>>(
            (const uint4*)hbuf, csr, off, (float4*)xbuf, (float4*)out, temp, l);
    }
}

// Round 7
// 367.080 us; speedup vs baseline: 8.1884x; 1.0852x over previous
//
#include <hip/hip_runtime.h>
#include <hip/hip_fp16.h>

#define NN 50000
#define NE 1600000
#define DD 64
#define NBK 782      // ceil(NN/64) buckets of 64 dst nodes
#define TILE 4096    // edges per binning block
#define NTB 391      // ceil(NE/TILE)
#define SCAP 3072    // fixed per-bucket capacity (mean 2048, sigma ~45; 22 sigma headroom)

// out = x*temp[0]; xbuf = x
__global__ __launch_bounds__(256) void init_kernel(const float4* __restrict__ x,
                                                   float4* __restrict__ out,
                                                   float4* __restrict__ xbuf,
                                                   const float* __restrict__ temp) {
    int i = blockIdx.x * blockDim.x + threadIdx.x;
    const int n4 = NN * DD / 4;
    if (i < n4) {
        float t0 = temp[0];
        float4 v = x[i];
        xbuf[i] = v;
        float4 o;
        o.x = v.x * t0; o.y = v.y * t0; o.z = v.z * t0; o.w = v.w * t0;
        out[i] = o;
    }
}

// tile -> LDS reorder by bucket -> burst write into fixed-stride bucket regions.
// Entry: x = src | dst<<16 (both <65536), y = w bits.
__global__ __launch_bounds__(256) void fill_kernel(const int* __restrict__ src,
                                                   const int* __restrict__ dst,
                                                   const float* __restrict__ w,
                                                   int* __restrict__ gcur,
                                                   uint2* __restrict__ tmp) {
    __shared__ uint2 data[TILE];        // 32 KB
    __shared__ int cnt[NBK], bas[NBK], rnk[NBK];
    __shared__ int sc[1024];
    int t = threadIdx.x;
    for (int k = t; k < NBK; k += 256) { cnt[k] = 0; rnk[k] = 0; }
    __syncthreads();
    int base = blockIdx.x * TILE;
    uint2 er[TILE / 256];
#pragma unroll
    for (int k = 0; k < TILE / 256; ++k) {
        int i = base + k * 256 + t;
        if (i < NE) {
            uint2 e;
            e.x = (unsigned int)src[i] | ((unsigned int)dst[i] << 16);
            e.y = (unsigned int)__float_as_int(w[i]);
            er[k] = e;
            atomicAdd(&cnt[e.x >> 22], 1);   // bucket = dst>>6
        }
    }
    __syncthreads();
    // reserve space within each bucket's fixed region
    for (int k = t; k < NBK; k += 256) {
        int c = cnt[k];
        bas[k] = c ? atomicAdd(&gcur[k], c) : 0;
    }
    // local exclusive scan of cnt (Hillis-Steele over 1024 slots)
    for (int k = t; k < 1024; k += 256) sc[k] = (k < NBK) ? cnt[k] : 0;
    __syncthreads();
    for (int s = 1; s < 1024; s <<= 1) {
        int v0[4];
#pragma unroll
        for (int j = 0; j < 4; ++j) {
            int idx = t + j * 256;
            v0[j] = (idx >= s) ? sc[idx - s] : 0;
        }
        __syncthreads();
#pragma unroll
        for (int j = 0; j < 4; ++j) sc[t + j * 256] += v0[j];
        __syncthreads();
    }
    // place entries bucket-contiguously in LDS
#pragma unroll
    for (int k = 0; k < TILE / 256; ++k) {
        int i = base + k * 256 + t;
        if (i < NE) {
            uint2 e = er[k];
            int b = e.x >> 22;
            int r = atomicAdd(&rnk[b], 1);
            data[(sc[b] - cnt[b]) + r] = e;
        }
    }
    __syncthreads();
    // sequential write-out: same-line stores are temporally adjacent
    int tot = NE - base; if (tot > TILE) tot = TILE;
    for (int idx = t; idx < tot; idx += 256) {
        uint2 e = data[idx];
        int b = e.x >> 22;
        int lb = sc[b] - cnt[b];
        tmp[(size_t)b * SCAP + bas[b] + (idx - lb)] = e;
    }
}

// block = bucket: LDS counting-sort by dst-local, emit packed 4B CSR (strided
// layout) + per-node (beg,end) offsets
__global__ __launch_bounds__(256) void sort_kernel(const uint2* __restrict__ tmp,
                                                   const int* __restrict__ gcur,
                                                   unsigned int* __restrict__ csr,
                                                   int2* __restrict__ off2) {
    __shared__ unsigned int pk[SCAP];
    __shared__ unsigned char dl[SCAP];
    __shared__ unsigned int outp[SCAP];
    __shared__ int cnt[64], nb[64], pos[64];
    int b = blockIdx.x, t = threadIdx.x;
    int beg = b * SCAP, n = gcur[b];
    if (t < 64) cnt[t] = 0;
    __syncthreads();
    for (int i = t; i < n; i += 256) {
        uint2 e = tmp[beg + i];
        unsigned int s = e.x & 0xffffu;
        unsigned int d = (e.x >> 16) & 63u;
        unsigned int wh = (unsigned int)__half_as_ushort(
            __float2half_rn(__int_as_float((int)e.y)));
        pk[i] = s | (wh << 16);
        dl[i] = (unsigned char)d;
        atomicAdd(&cnt[(int)d], 1);
    }
    __syncthreads();
    if (t == 0) {
        int a = 0;
        for (int k = 0; k < 64; ++k) { nb[k] = a; pos[k] = a; a += cnt[k]; }
    }
    __syncthreads();
    for (int i = t; i < n; i += 256) {
        int d = dl[i];
        int r = atomicAdd(&pos[d], 1);
        outp[r] = pk[i];
    }
    __syncthreads();
    for (int i = t; i < n; i += 256) csr[beg + i] = outp[i];
    if (t < 64) {
        int node = b * 64 + t;
        if (node < NN) {
            int2 oe;
            oe.x = beg + nb[t];
            oe.y = beg + nb[t] + cnt[t];
            off2[node] = oe;
        }
    }
}

// h = x @ W^T + b, h stored fp16 ; 32 nodes/block, wave per node
__global__ __launch_bounds__(256) void gemm_kernel(const float* __restrict__ x,
                                                   const float* __restrict__ Wl,
                                                   const float* __restrict__ bl,
                                                   __half* __restrict__ h) {
    __shared__ float WT[64 * 65];   // WT[d*65+o] = W[o*64+d]
    __shared__ float bs[64];
    int t = threadIdx.x;
#pragma unroll
    for (int k = 0; k < 16; ++k) {
        int idx = t + k * 256;
        int o = idx >> 6, d = idx & 63;
        WT[d * 65 + o] = Wl[o * 64 + d];
    }
    if (t < 64) bs[t] = bl[t];
    __syncthreads();
    int o = t & 63;
    int r = t >> 6;
#pragma unroll
    for (int p = 0; p < 8; ++p) {
        int node = blockIdx.x * 32 + p * 4 + r;
        if (node < NN) {
            const float* xr = x + (size_t)node * 64;
            float acc = bs[o];
#pragma unroll
            for (int d = 0; d < 64; ++d)
                acc += xr[d] * WT[d * 65 + o];   // xr[d] wave-uniform -> broadcast
            h[(size_t)node * 64 + o] = __float2half_rn(acc);
        }
    }
}

// pull, eighth-wave fp16: wave = 1 node; lane = (oct=lane>>3, sub=lane&7).
__global__ __launch_bounds__(256) void pull_kernel(const uint4* __restrict__ h16,
                                                   const unsigned int* __restrict__ csr,
                                                   const int2* __restrict__ off2,
                                                   float4* __restrict__ xbuf,
                                                   float4* __restrict__ out,
                                                   const float* __restrict__ temp,
                                                   int layer) {
    int node = blockIdx.x * 4 + (threadIdx.x >> 6);
    int lane = threadIdx.x & 63;
    if (node >= NN) return;
    int oct = lane >> 3, sub = lane & 7;
    int2 oe = off2[node];
    int beg = oe.x, end = oe.y;
    float acc[8];
#pragma unroll
    for (int k = 0; k < 8; ++k) acc[k] = 0.f;

    for (int base = beg; base < end; base += 64) {
        int cnt = end - base;
        if (cnt > 64) cnt = 64;
        unsigned int e = 0;                    // src=0, w=+0 -> no-op for idle lanes
        if (lane < cnt) e = csr[base + lane];
        int cntp = (cnt + 7) & ~7;
        for (int j = 0; j < cntp; j += 8) {
            unsigned int ej = (unsigned int)__shfl((int)e, j + oct);
            int   s  = (int)(ej & 0xffffu);
            float wj = __half2float(__ushort_as_half((unsigned short)(ej >> 16)));
            uint4 hv = h16[(size_t)s * 8 + sub];
            const __half2* hp = (const __half2*)&hv;
#pragma unroll
            for (int k = 0; k < 4; ++k) {
                float2 f = __half22float2(hp[k]);
                acc[2 * k]     += wj * f.x;
                acc[2 * k + 1] += wj * f.y;
            }
        }
    }
#pragma unroll
    for (int m = 8; m < 64; m <<= 1) {
#pragma unroll
        for (int k = 0; k < 8; ++k) acc[k] += __shfl_xor(acc[k], m);
    }
    if (oct == 0) {
        float tk = temp[layer + 1];
        float4 v0, v1;
        v0.x = fmaxf(acc[0], 0.f); v0.y = fmaxf(acc[1], 0.f);
        v0.z = fmaxf(acc[2], 0.f); v0.w = fmaxf(acc[3], 0.f);
        v1.x = fmaxf(acc[4], 0.f); v1.y = fmaxf(acc[5], 0.f);
        v1.z = fmaxf(acc[6], 0.f); v1.w = fmaxf(acc[7], 0.f);
        int gi = node * 16 + sub * 2;
        xbuf[gi]     = v0;
        xbuf[gi + 1] = v1;
        float4 o0 = out[gi], o1 = out[gi + 1];
        o0.x += v0.x * tk; o0.y += v0.y * tk; o0.z += v0.z * tk; o0.w += v0.w * tk;
        o1.x += v1.x * tk; o1.y += v1.y * tk; o1.z += v1.z * tk; o1.w += v1.w * tk;
        out[gi]     = o0;
        out[gi + 1] = o1;
    }
}

extern "C" void kernel_launch(void* const* d_in, const int* in_sizes, int n_in,
                              void* d_out, int out_size, void* d_ws, size_t ws_size,
                              hipStream_t stream) {
    const float* x    = (const float*)d_in[0];
    const float* w    = (const float*)d_in[1];
    const float* W    = (const float*)d_in[2];
    const float* b    = (const float*)d_in[3];
    const float* temp = (const float*)d_in[4];
    const int*   src  = (const int*)d_in[5];
    const int*   dst  = (const int*)d_in[6];
    float* out = (float*)d_out;

    // workspace layout (~49 MB)
    float*        xbuf = (float*)d_ws;                             // NN*DD f32
    __half*       hbuf = (__half*)(xbuf + (size_t)NN * DD);        // NN*DD f16
    unsigned int* csr  = (unsigned int*)(hbuf + (size_t)NN * DD);  // NBK*SCAP u32
    uint2*        tmp  = (uint2*)(csr + (size_t)NBK * SCAP);       // NBK*SCAP uint2
    int*          gcur = (int*)(tmp + (size_t)NBK * SCAP);         // NBK
    int2*         off2 = (int2*)(gcur + NBK);                      // NN

    // ---- CSR build (no count/scan passes: fixed-capacity bucket regions) ----
    hipMemsetAsync(gcur, 0, (size_t)NBK * sizeof(int), stream);
    fill_kernel<<<NTB, 256, 0, stream>>>(src, dst, w, gcur, tmp);
    sort_kernel<<<NBK, 256, 0, stream>>>(tmp, gcur, csr, off2);

    // ---- init ----
    const int n4 = NN * DD / 4;
    init_kernel<<<(n4 + 255) / 256, 256, 0, stream>>>(
        (const float4*)x, (float4*)out, (float4*)xbuf, temp);

    // ---- layers ----
    for (int l = 0; l < 4; ++l) {
        gemm_kernel<<<(NN + 31) / 32, 256, 0, stream>>>(
            xbuf, W + (size_t)l * DD * DD, b + (size_t)l * DD, hbuf);
        pull_kernel<<<(NN + 3) / 4, 256, 0, stream>>>(
            (const uint4*)hbuf, csr, off2, (float4*)xbuf, (float4*)out, temp, l);
    }
}

// Round 8
// 337.027 us; speedup vs baseline: 8.9186x; 1.0892x over previous
//
#include <hip/hip_runtime.h>
#include <hip/hip_fp16.h>

#define NN 50000
#define NE 1600000
#define DD 64
#define NBK 782      // ceil(NN/64) buckets of 64 dst nodes
#define TILE 4096    // edges per binning block
#define NTB 391      // ceil(NE/TILE)
#define SCAP 3072    // fixed per-bucket capacity (mean 2048, sigma ~45)

typedef _Float16 half8 __attribute__((ext_vector_type(8)));
typedef float float4v __attribute__((ext_vector_type(4)));

// out = x*temp[0] (f32); xh = x as f16
__global__ __launch_bounds__(256) void init_kernel(const float4* __restrict__ x,
                                                   float4* __restrict__ out,
                                                   uint2* __restrict__ xh2,
                                                   const float* __restrict__ temp) {
    int i = blockIdx.x * blockDim.x + threadIdx.x;
    const int n4 = NN * DD / 4;
    if (i < n4) {
        float t0 = temp[0];
        float4 v = x[i];
        __half2 p[2];
        p[0] = __floats2half2_rn(v.x, v.y);
        p[1] = __floats2half2_rn(v.z, v.w);
        xh2[i] = *(const uint2*)p;
        float4 o;
        o.x = v.x * t0; o.y = v.y * t0; o.z = v.z * t0; o.w = v.w * t0;
        out[i] = o;
    }
}

// tile -> LDS reorder by bucket -> burst write into fixed-stride bucket regions.
__global__ __launch_bounds__(256) void fill_kernel(const int* __restrict__ src,
                                                   const int* __restrict__ dst,
                                                   const float* __restrict__ w,
                                                   int* __restrict__ gcur,
                                                   uint2* __restrict__ tmp) {
    __shared__ uint2 data[TILE];        // 32 KB
    __shared__ int cnt[NBK], bas[NBK], rnk[NBK];
    __shared__ int sc[1024];
    int t = threadIdx.x;
    for (int k = t; k < NBK; k += 256) { cnt[k] = 0; rnk[k] = 0; }
    __syncthreads();
    int base = blockIdx.x * TILE;
    uint2 er[TILE / 256];
#pragma unroll
    for (int k = 0; k < TILE / 256; ++k) {
        int i = base + k * 256 + t;
        if (i < NE) {
            uint2 e;
            e.x = (unsigned int)src[i] | ((unsigned int)dst[i] << 16);
            e.y = (unsigned int)__float_as_int(w[i]);
            er[k] = e;
            atomicAdd(&cnt[e.x >> 22], 1);   // bucket = dst>>6
        }
    }
    __syncthreads();
    for (int k = t; k < NBK; k += 256) {
        int c = cnt[k];
        bas[k] = c ? atomicAdd(&gcur[k], c) : 0;
    }
    for (int k = t; k < 1024; k += 256) sc[k] = (k < NBK) ? cnt[k] : 0;
    __syncthreads();
    for (int s = 1; s < 1024; s <<= 1) {
        int v0[4];
#pragma unroll
        for (int j = 0; j < 4; ++j) {
            int idx = t + j * 256;
            v0[j] = (idx >= s) ? sc[idx - s] : 0;
        }
        __syncthreads();
#pragma unroll
        for (int j = 0; j < 4; ++j) sc[t + j * 256] += v0[j];
        __syncthreads();
    }
#pragma unroll
    for (int k = 0; k < TILE / 256; ++k) {
        int i = base + k * 256 + t;
        if (i < NE) {
            uint2 e = er[k];
            int b = e.x >> 22;
            int r = atomicAdd(&rnk[b], 1);
            data[(sc[b] - cnt[b]) + r] = e;
        }
    }
    __syncthreads();
    int tot = NE - base; if (tot > TILE) tot = TILE;
    for (int idx = t; idx < tot; idx += 256) {
        uint2 e = data[idx];
        int b = e.x >> 22;
        int lb = sc[b] - cnt[b];
        tmp[(size_t)b * SCAP + bas[b] + (idx - lb)] = e;
    }
}

// block = bucket: LDS counting-sort by dst-local, emit packed 4B CSR + (beg,end)
__global__ __launch_bounds__(256) void sort_kernel(const uint2* __restrict__ tmp,
                                                   const int* __restrict__ gcur,
                                                   unsigned int* __restrict__ csr,
                                                   int2* __restrict__ off2) {
    __shared__ unsigned int pk[SCAP];
    __shared__ unsigned char dl[SCAP];
    __shared__ unsigned int outp[SCAP];
    __shared__ int cnt[64], nb[64], pos[64];
    int b = blockIdx.x, t = threadIdx.x;
    int beg = b * SCAP, n = gcur[b];
    if (t < 64) cnt[t] = 0;
    __syncthreads();
    for (int i = t; i < n; i += 256) {
        uint2 e = tmp[beg + i];
        unsigned int s = e.x & 0xffffu;
        unsigned int d = (e.x >> 16) & 63u;
        unsigned int wh = (unsigned int)__half_as_ushort(
            __float2half_rn(__int_as_float((int)e.y)));
        pk[i] = s | (wh << 16);
        dl[i] = (unsigned char)d;
        atomicAdd(&cnt[(int)d], 1);
    }
    __syncthreads();
    if (t == 0) {
        int a = 0;
        for (int k = 0; k < 64; ++k) { nb[k] = a; pos[k] = a; a += cnt[k]; }
    }
    __syncthreads();
    for (int i = t; i < n; i += 256) {
        int d = dl[i];
        int r = atomicAdd(&pos[d], 1);
        outp[r] = pk[i];
    }
    __syncthreads();
    for (int i = t; i < n; i += 256) csr[beg + i] = outp[i];
    if (t < 64) {
        int node = b * 64 + t;
        if (node < NN) {
            int2 oe;
            oe.x = beg + nb[t];
            oe.y = beg + nb[t] + cnt[t];
            off2[node] = oe;
        }
    }
}

// MFMA GEMM: h = x @ W^T + b, all f16 inputs, f32 accumulate, f16 output.
// Block = 64 nodes (4 waves x 16). W pre-swizzled into fragment order in LDS.
__global__ __launch_bounds__(256) void gemm_mfma(const _Float16* __restrict__ xh,
                                                 const float* __restrict__ Wl,
                                                 const float* __restrict__ bl,
                                                 _Float16* __restrict__ h) {
    __shared__ _Float16 Wswz[4096];   // [nt][kt][lane][j] = W[nt*16+(lane&15)][kt*32+(lane>>4)*8+j]
    __shared__ float bs[64];
    int t = threadIdx.x;
#pragma unroll
    for (int k = 0; k < 16; ++k) {
        int flat = t + k * 256;
        int j = flat & 7, lane_ = (flat >> 3) & 63, kt = (flat >> 9) & 1, nt = flat >> 10;
        int n = nt * 16 + (lane_ & 15);
        int kk = kt * 32 + ((lane_ >> 4) * 8) + j;
        Wswz[flat] = (_Float16)Wl[n * 64 + kk];
    }
    if (t < 64) bs[t] = bl[t];
    __syncthreads();
    int wave = t >> 6, lane = t & 63;
    int m = lane & 15, q = lane >> 4;
    int node0 = blockIdx.x * 64 + wave * 16;
    int arow = node0 + m; if (arow >= NN) arow = NN - 1;
    const uint4* xr = (const uint4*)(xh + (size_t)arow * 64);
    uint4 a0u = xr[q];        // kt=0: k = q*8 .. q*8+7
    uint4 a1u = xr[4 + q];    // kt=1
    half8 a0 = __builtin_bit_cast(half8, a0u);
    half8 a1 = __builtin_bit_cast(half8, a1u);
    const half8* Wf = (const half8*)Wswz;
    float4v acc[4];
#pragma unroll
    for (int nt = 0; nt < 4; ++nt) acc[nt] = (float4v){0.f, 0.f, 0.f, 0.f};
#pragma unroll
    for (int nt = 0; nt < 4; ++nt) {
        half8 b0 = Wf[(nt * 2 + 0) * 64 + lane];
        half8 b1 = Wf[(nt * 2 + 1) * 64 + lane];
        acc[nt] = __builtin_amdgcn_mfma_f32_16x16x32_f16(a0, b0, acc[nt], 0, 0, 0);
        acc[nt] = __builtin_amdgcn_mfma_f32_16x16x32_f16(a1, b1, acc[nt], 0, 0, 0);
    }
    // D: row = q*4+r (node), col = m (output within nt-tile)
#pragma unroll
    for (int nt = 0; nt < 4; ++nt) {
#pragma unroll
        for (int r = 0; r < 4; ++r) {
            int node = node0 + q * 4 + r;
            if (node < NN)
                h[(size_t)node * 64 + nt * 16 + m] =
                    (_Float16)(acc[nt][r] + bs[nt * 16 + m]);
        }
    }
}

// pull, half-row waves: wave = (node, half). lane = (g=lane>>2, sub=lane&3).
// Each g processes a different edge; 4 lanes cover a 64B half-row (1 line/edge).
__global__ __launch_bounds__(256) void pull_kernel(const uint4* __restrict__ h16,
                                                   const unsigned int* __restrict__ csr,
                                                   const int2* __restrict__ off2,
                                                   uint4* __restrict__ xh4,
                                                   float4* __restrict__ out,
                                                   const float* __restrict__ temp,
                                                   int layer) {
    int wid = blockIdx.x * 4 + (threadIdx.x >> 6);
    int node = wid >> 1, half = wid & 1;
    if (node >= NN) return;
    int lane = threadIdx.x & 63;
    int g = lane >> 2, sub = lane & 3;
    int2 oe = off2[node];
    int beg = oe.x, end = oe.y;
    float acc[8];
#pragma unroll
    for (int k = 0; k < 8; ++k) acc[k] = 0.f;

    for (int base = beg; base < end; base += 64) {
        int cnt = end - base;
        if (cnt > 64) cnt = 64;
        unsigned int e = 0;                    // src=0, w=+0 -> no-op for idle lanes
        if (lane < cnt) e = csr[base + lane];
        int cntp = (cnt + 15) & ~15;
        for (int j = 0; j < cntp; j += 16) {
            unsigned int ej = (unsigned int)__shfl((int)e, j + g);
            int   s  = (int)(ej & 0xffffu);
            float wj = __half2float(__ushort_as_half((unsigned short)(ej >> 16)));
            uint4 hv = h16[(size_t)s * 8 + half * 4 + sub];
            const __half2* hp = (const __half2*)&hv;
#pragma unroll
            for (int k = 0; k < 4; ++k) {
                float2 f = __half22float2(hp[k]);
                acc[2 * k]     += wj * f.x;
                acc[2 * k + 1] += wj * f.y;
            }
        }
    }
    // reduce partial sums across the 16 g-groups (strides 4,8,16,32)
#pragma unroll
    for (int m = 4; m < 64; m <<= 1) {
#pragma unroll
        for (int k = 0; k < 8; ++k) acc[k] += __shfl_xor(acc[k], m);
    }
    if (g == 0) {   // lanes 0..3; features = half*32 + sub*8 + k
        float tk = temp[layer + 1];
        float v[8];
#pragma unroll
        for (int k = 0; k < 8; ++k) v[k] = fmaxf(acc[k], 0.f);
        __half2 p[4];
#pragma unroll
        for (int k = 0; k < 4; ++k) p[k] = __floats2half2_rn(v[2 * k], v[2 * k + 1]);
        xh4[(size_t)node * 8 + half * 4 + sub] = *(const uint4*)p;
        int gi = node * 16 + half * 8 + sub * 2;
        float4 o0 = out[gi], o1 = out[gi + 1];
        o0.x += v[0] * tk; o0.y += v[1] * tk; o0.z += v[2] * tk; o0.w += v[3] * tk;
        o1.x += v[4] * tk; o1.y += v[5] * tk; o1.z += v[6] * tk; o1.w += v[7] * tk;
        out[gi]     = o0;
        out[gi + 1] = o1;
    }
}

extern "C" void kernel_launch(void* const* d_in, const int* in_sizes, int n_in,
                              void* d_out, int out_size, void* d_ws, size_t ws_size,
                              hipStream_t stream) {
    const float* x    = (const float*)d_in[0];
    const float* w    = (const float*)d_in[1];
    const float* W    = (const float*)d_in[2];
    const float* b    = (const float*)d_in[3];
    const float* temp = (const float*)d_in[4];
    const int*   src  = (const int*)d_in[5];
    const int*   dst  = (const int*)d_in[6];
    float* out = (float*)d_out;

    // workspace layout (~42 MB)
    _Float16*     xh   = (_Float16*)d_ws;                          // NN*DD f16
    _Float16*     hbuf = xh + (size_t)NN * DD;                     // NN*DD f16
    unsigned int* csr  = (unsigned int*)(hbuf + (size_t)NN * DD);  // NBK*SCAP u32
    uint2*        tmp  = (uint2*)(csr + (size_t)NBK * SCAP);       // NBK*SCAP uint2
    int*          gcur = (int*)(tmp + (size_t)NBK * SCAP);         // NBK
    int2*         off2 = (int2*)(gcur + NBK);                      // NN

    // ---- CSR build ----
    hipMemsetAsync(gcur, 0, (size_t)NBK * sizeof(int), stream);
    fill_kernel<<<NTB, 256, 0, stream>>>(src, dst, w, gcur, tmp);
    sort_kernel<<<NBK, 256, 0, stream>>>(tmp, gcur, csr, off2);

    // ---- init ----
    const int n4 = NN * DD / 4;
    init_kernel<<<(n4 + 255) / 256, 256, 0, stream>>>(
        (const float4*)x, (float4*)out, (uint2*)xh, temp);

    // ---- layers ----
    for (int l = 0; l < 4; ++l) {
        gemm_mfma<<<NBK, 256, 0, stream>>>(
            xh, W + (size_t)l * DD * DD, b + (size_t)l * DD, hbuf);
        pull_kernel<<<(2 * NN + 3) / 4, 256, 0, stream>>>(
            (const uint4*)hbuf, csr, off2, (uint4*)xh, (float4*)out, temp, l);
    }
}

// Round 9
// 258.340 us; speedup vs baseline: 11.6350x; 1.3046x over previous
//
#include <hip/hip_runtime.h>
#include <hip/hip_fp16.h>

#define NN 50000
#define NE 1600000
#define DD 64
#define NBK 782      // ceil(NN/64) buckets of 64 dst nodes
#define TILE 4096    // edges per binning block
#define NTB 391      // ceil(NE/TILE)
#define SCAP 3072    // fixed per-bucket capacity (mean 2048, sigma ~45)

typedef _Float16 half8 __attribute__((ext_vector_type(8)));
typedef float float4v __attribute__((ext_vector_type(4)));

// pre-swizzle W (all 4 layers) into MFMA B-fragment order, fp16.
// flat = ((nt*2+kt)*64 + lane)*8 + j  ->  W[l][n=nt*16+(lane&15)][k=kt*32+(lane>>4)*8+j]
__global__ __launch_bounds__(256) void wswz_kernel(const float* __restrict__ W,
                                                   _Float16* __restrict__ Wswz) {
    int flat = blockIdx.x * 256 + threadIdx.x;   // 4*4096 total
    int l = flat >> 12, r = flat & 4095;
    int j = r & 7, lane = (r >> 3) & 63, kt = (r >> 9) & 1, nt = r >> 10;
    int n = nt * 16 + (lane & 15);
    int k = kt * 32 + ((lane >> 4) * 8) + j;
    Wswz[flat] = (_Float16)W[l * 4096 + n * 64 + k];
}

// tile -> LDS reorder by bucket -> burst write into fixed-stride bucket regions.
__global__ __launch_bounds__(256) void fill_kernel(const int* __restrict__ src,
                                                   const int* __restrict__ dst,
                                                   const float* __restrict__ w,
                                                   int* __restrict__ gcur,
                                                   uint2* __restrict__ tmp) {
    __shared__ uint2 data[TILE];        // 32 KB
    __shared__ int cnt[NBK], bas[NBK], rnk[NBK];
    __shared__ int sc[1024];
    int t = threadIdx.x;
    for (int k = t; k < NBK; k += 256) { cnt[k] = 0; rnk[k] = 0; }
    __syncthreads();
    int base = blockIdx.x * TILE;
    uint2 er[TILE / 256];
#pragma unroll
    for (int k = 0; k < TILE / 256; ++k) {
        int i = base + k * 256 + t;
        if (i < NE) {
            uint2 e;
            e.x = (unsigned int)src[i] | ((unsigned int)dst[i] << 16);
            e.y = (unsigned int)__float_as_int(w[i]);
            er[k] = e;
            atomicAdd(&cnt[e.x >> 22], 1);   // bucket = dst>>6
        }
    }
    __syncthreads();
    for (int k = t; k < NBK; k += 256) {
        int c = cnt[k];
        bas[k] = c ? atomicAdd(&gcur[k], c) : 0;
    }
    for (int k = t; k < 1024; k += 256) sc[k] = (k < NBK) ? cnt[k] : 0;
    __syncthreads();
    for (int s = 1; s < 1024; s <<= 1) {
        int v0[4];
#pragma unroll
        for (int j = 0; j < 4; ++j) {
            int idx = t + j * 256;
            v0[j] = (idx >= s) ? sc[idx - s] : 0;
        }
        __syncthreads();
#pragma unroll
        for (int j = 0; j < 4; ++j) sc[t + j * 256] += v0[j];
        __syncthreads();
    }
#pragma unroll
    for (int k = 0; k < TILE / 256; ++k) {
        int i = base + k * 256 + t;
        if (i < NE) {
            uint2 e = er[k];
            int b = e.x >> 22;
            int r = atomicAdd(&rnk[b], 1);
            data[(sc[b] - cnt[b]) + r] = e;
        }
    }
    __syncthreads();
    int tot = NE - base; if (tot > TILE) tot = TILE;
    for (int idx = t; idx < tot; idx += 256) {
        uint2 e = data[idx];
        int b = e.x >> 22;
        int lb = sc[b] - cnt[b];
        tmp[(size_t)b * SCAP + bas[b] + (idx - lb)] = e;
    }
}

// block = bucket: two-pass (count, then rank+write; 2nd tmp read is L2-hot).
// Emits packed 4B CSR (src | w_fp16<<16) + per-node (beg,end).
__global__ __launch_bounds__(256) void sort_kernel(const uint2* __restrict__ tmp,
                                                   const int* __restrict__ gcur,
                                                   unsigned int* __restrict__ csr,
                                                   int2* __restrict__ off2) {
    __shared__ int cnt[64], nb[64], pos[64];
    int b = blockIdx.x, t = threadIdx.x;
    int beg = b * SCAP, n = gcur[b];
    if (t < 64) cnt[t] = 0;
    __syncthreads();
    for (int i = t; i < n; i += 256) {
        uint2 e = tmp[beg + i];
        atomicAdd(&cnt[(e.x >> 16) & 63u], 1);
    }
    __syncthreads();
    if (t == 0) {
        int a = 0;
        for (int k = 0; k < 64; ++k) { nb[k] = a; pos[k] = a; a += cnt[k]; }
    }
    __syncthreads();
    for (int i = t; i < n; i += 256) {
        uint2 e = tmp[beg + i];
        int d = (int)((e.x >> 16) & 63u);
        unsigned int wh = (unsigned int)__half_as_ushort(
            __float2half_rn(__int_as_float((int)e.y)));
        int r = atomicAdd(&pos[d], 1);
        csr[beg + r] = (e.x & 0xffffu) | (wh << 16);
    }
    __syncthreads();
    if (t < 64) {
        int node = b * 64 + t;
        if (node < NN) {
            int2 oe;
            oe.x = beg + nb[t];
            oe.y = beg + nb[t] + cnt[t];
            off2[node] = oe;
        }
    }
}

// MFMA GEMM: h = x @ W^T + b, f32 accumulate, f16 out. No LDS (W pre-swizzled).
// Block = 64 nodes (4 waves x 16). layer0: read f32 x; else f16 xh.
__global__ __launch_bounds__(256) void gemm_mfma(const _Float16* __restrict__ xh,
                                                 const float* __restrict__ x32,
                                                 const _Float16* __restrict__ Wg,
                                                 const float* __restrict__ bl,
                                                 _Float16* __restrict__ h,
                                                 int layer0) {
    int t = threadIdx.x;
    int wave = t >> 6, lane = t & 63;
    int m = lane & 15, q = lane >> 4;
    int node0 = blockIdx.x * 64 + wave * 16;
    int arow = node0 + m; if (arow >= NN) arow = NN - 1;
    half8 a0, a1;
    if (layer0) {
        const float4* xr = (const float4*)(x32 + (size_t)arow * 64);
        float4 f0 = xr[2 * q], f1 = xr[2 * q + 1];
        float4 f2 = xr[8 + 2 * q], f3 = xr[8 + 2 * q + 1];
        a0[0] = (_Float16)f0.x; a0[1] = (_Float16)f0.y; a0[2] = (_Float16)f0.z; a0[3] = (_Float16)f0.w;
        a0[4] = (_Float16)f1.x; a0[5] = (_Float16)f1.y; a0[6] = (_Float16)f1.z; a0[7] = (_Float16)f1.w;
        a1[0] = (_Float16)f2.x; a1[1] = (_Float16)f2.y; a1[2] = (_Float16)f2.z; a1[3] = (_Float16)f2.w;
        a1[4] = (_Float16)f3.x; a1[5] = (_Float16)f3.y; a1[6] = (_Float16)f3.z; a1[7] = (_Float16)f3.w;
    } else {
        const uint4* xr = (const uint4*)(xh + (size_t)arow * 64);
        a0 = __builtin_bit_cast(half8, xr[q]);
        a1 = __builtin_bit_cast(half8, xr[4 + q]);
    }
    const half8* Wf = (const half8*)Wg;
    float4v acc[4];
#pragma unroll
    for (int nt = 0; nt < 4; ++nt) acc[nt] = (float4v){0.f, 0.f, 0.f, 0.f};
#pragma unroll
    for (int nt = 0; nt < 4; ++nt) {
        half8 b0 = Wf[(nt * 2 + 0) * 64 + lane];
        half8 b1 = Wf[(nt * 2 + 1) * 64 + lane];
        acc[nt] = __builtin_amdgcn_mfma_f32_16x16x32_f16(a0, b0, acc[nt], 0, 0, 0);
        acc[nt] = __builtin_amdgcn_mfma_f32_16x16x32_f16(a1, b1, acc[nt], 0, 0, 0);
    }
#pragma unroll
    for (int nt = 0; nt < 4; ++nt) {
        float bv = bl[nt * 16 + m];
#pragma unroll
        for (int r = 0; r < 4; ++r) {
            int node = node0 + q * 4 + r;
            if (node < NN)
                h[(size_t)node * 64 + nt * 16 + m] = (_Float16)(acc[nt][r] + bv);
        }
    }
}

// pull, 4 nodes/wave: lane = (slot=lane>>4, g=(lane>>3)&1, sub=lane&7).
// Per iter: 8 full 128B rows gathered (8 edges x 64 feats), fma_mix f16->f32.
// Reduction: 1 stride (8 shfl). layer0: out = x*t0 + v*t1.
__global__ __launch_bounds__(256) void pull_kernel(const uint4* __restrict__ h16,
                                                   const unsigned int* __restrict__ csr,
                                                   const int2* __restrict__ off2,
                                                   uint4* __restrict__ xh4,
                                                   float4* __restrict__ out,
                                                   const float4* __restrict__ x32,
                                                   const float* __restrict__ temp,
                                                   int layer) {
    int t = threadIdx.x;
    int lane = t & 63;
    int slot = lane >> 4, g = (lane >> 3) & 1, sub = lane & 7;
    int node0 = blockIdx.x * 16 + (t >> 6) * 4;   // 4 nodes per wave
    int node = node0 + slot;
    int nclamp = node < NN ? node : NN - 1;
    int2 oe = off2[nclamp];
    int deg = (node < NN) ? (oe.y - oe.x) : 0;
    int beg = oe.x;
    // wave-uniform max degree over the 4 slots
    int dmax = deg;
    dmax = max(dmax, __shfl_xor(dmax, 16));
    dmax = max(dmax, __shfl_xor(dmax, 32));
    int sl = lane & 15;
    float acc[8];
#pragma unroll
    for (int k = 0; k < 8; ++k) acc[k] = 0.f;

    int chunks = (dmax + 15) >> 4;
    for (int c = 0; c < chunks; ++c) {
        int idx = (c << 4) + sl;
        unsigned int e = 0;                 // src=0, w=+0 for idle lanes
        if (idx < deg) e = csr[beg + idx];
#pragma unroll
        for (int j = 0; j < 8; ++j) {
            unsigned int ej = (unsigned int)__shfl((int)e, (slot << 4) + j * 2 + g);
            int s = (int)(ej & 0xffffu);
            __half wh = __ushort_as_half((unsigned short)(ej >> 16));
            uint4 hv = h16[(size_t)s * 8 + sub];
            const __half* hp = (const __half*)&hv;
            float wf = (float)wh;
#pragma unroll
            for (int k = 0; k < 8; ++k)
                acc[k] += (float)hp[k] * wf;   // v_fma_mix_f32
        }
    }
    // reduce over g (stride 8)
#pragma unroll
    for (int k = 0; k < 8; ++k) acc[k] += __shfl_xor(acc[k], 8);

    if (g == 0 && node < NN) {   // lanes sl<8: feats sub*8 .. sub*8+7
        float tk = temp[layer + 1];
        float v[8];
#pragma unroll
        for (int k = 0; k < 8; ++k) v[k] = fmaxf(acc[k], 0.f);
        __half2 p[4];
#pragma unroll
        for (int k = 0; k < 4; ++k) p[k] = __floats2half2_rn(v[2 * k], v[2 * k + 1]);
        xh4[(size_t)node * 8 + sub] = *(const uint4*)p;
        int gi = node * 16 + sub * 2;
        float4 o0, o1;
        if (layer == 0) {
            float t0 = temp[0];
            float4 a = x32[gi], bq = x32[gi + 1];
            o0.x = a.x * t0;  o0.y = a.y * t0;  o0.z = a.z * t0;  o0.w = a.w * t0;
            o1.x = bq.x * t0; o1.y = bq.y * t0; o1.z = bq.z * t0; o1.w = bq.w * t0;
        } else {
            o0 = out[gi]; o1 = out[gi + 1];
        }
        o0.x += v[0] * tk; o0.y += v[1] * tk; o0.z += v[2] * tk; o0.w += v[3] * tk;
        o1.x += v[4] * tk; o1.y += v[5] * tk; o1.z += v[6] * tk; o1.w += v[7] * tk;
        out[gi]     = o0;
        out[gi + 1] = o1;
    }
}

extern "C" void kernel_launch(void* const* d_in, const int* in_sizes, int n_in,
                              void* d_out, int out_size, void* d_ws, size_t ws_size,
                              hipStream_t stream) {
    const float* x    = (const float*)d_in[0];
    const float* w    = (const float*)d_in[1];
    const float* W    = (const float*)d_in[2];
    const float* b    = (const float*)d_in[3];
    const float* temp = (const float*)d_in[4];
    const int*   src  = (const int*)d_in[5];
    const int*   dst  = (const int*)d_in[6];
    float* out = (float*)d_out;

    // workspace layout (~42 MB)
    _Float16*     xh   = (_Float16*)d_ws;                          // NN*DD f16
    _Float16*     hbuf = xh + (size_t)NN * DD;                     // NN*DD f16
    unsigned int* csr  = (unsigned int*)(hbuf + (size_t)NN * DD);  // NBK*SCAP u32
    uint2*        tmp  = (uint2*)(csr + (size_t)NBK * SCAP);       // NBK*SCAP uint2
    int*          gcur = (int*)(tmp + (size_t)NBK * SCAP);         // NBK
    int2*         off2 = (int2*)(gcur + NBK);                      // NN
    _Float16*     Wswz = (_Float16*)(off2 + NN);                   // 4*4096 f16

    // ---- CSR build + W pre-swizzle ----
    hipMemsetAsync(gcur, 0, (size_t)NBK * sizeof(int), stream);
    wswz_kernel<<<64, 256, 0, stream>>>(W, Wswz);
    fill_kernel<<<NTB, 256, 0, stream>>>(src, dst, w, gcur, tmp);
    sort_kernel<<<NBK, 256, 0, stream>>>(tmp, gcur, csr, off2);

    // ---- layers (no init kernel: layer0 reads x directly) ----
    for (int l = 0; l < 4; ++l) {
        gemm_mfma<<<NBK, 256, 0, stream>>>(
            xh, x, Wswz + (size_t)l * 4096, b + (size_t)l * DD, hbuf, l == 0);
        pull_kernel<<<(NN + 15) / 16, 256, 0, stream>>>(
            (const uint4*)hbuf, csr, off2, (uint4*)xh, (float4*)out,
            (const float4*)x, temp, l);
    }
}

// Round 11
// 234.000 us; speedup vs baseline: 12.8453x; 1.1040x over previous
//
#include <hip/hip_runtime.h>
#include <hip/hip_fp16.h>

#define NN 50000
#define NE 1600000
#define DD 64
#define NBK 782      // ceil(NN/64) buckets of 64 dst nodes
#define TILE 4096    // edges per binning block
#define NTB 391      // ceil(NE/TILE)
#define SCAP 3072    // fixed per-bucket capacity (mean 2048, sigma ~45)

typedef _Float16 half8 __attribute__((ext_vector_type(8)));
typedef float float4v __attribute__((ext_vector_type(4)));

// pre-swizzle W (all 4 layers) into MFMA B-fragment order, fp16.
// flat = ((nt*2+kt)*64 + lane)*8 + j  ->  W[l][n=nt*16+(lane&15)][k=kt*32+(lane>>4)*8+j]
__global__ __launch_bounds__(256) void wswz_kernel(const float* __restrict__ W,
                                                   _Float16* __restrict__ Wswz) {
    int flat = blockIdx.x * 256 + threadIdx.x;   // 4*4096 total
    int l = flat >> 12, r = flat & 4095;
    int j = r & 7, lane = (r >> 3) & 63, kt = (r >> 9) & 1, nt = r >> 10;
    int n = nt * 16 + (lane & 15);
    int k = kt * 32 + ((lane >> 4) * 8) + j;
    Wswz[flat] = (_Float16)W[l * 4096 + n * 64 + k];
}

// tile -> LDS reorder by bucket -> burst write into fixed-stride bucket regions.
__global__ __launch_bounds__(256) void fill_kernel(const int* __restrict__ src,
                                                   const int* __restrict__ dst,
                                                   const float* __restrict__ w,
                                                   int* __restrict__ gcur,
                                                   uint2* __restrict__ tmp) {
    __shared__ uint2 data[TILE];        // 32 KB
    __shared__ int cnt[NBK], bas[NBK], rnk[NBK];
    __shared__ int sc[1024];
    int t = threadIdx.x;
    for (int k = t; k < NBK; k += 256) { cnt[k] = 0; rnk[k] = 0; }
    __syncthreads();
    int base = blockIdx.x * TILE;
    uint2 er[TILE / 256];
#pragma unroll
    for (int k = 0; k < TILE / 256; ++k) {
        int i = base + k * 256 + t;
        if (i < NE) {
            uint2 e;
            e.x = (unsigned int)src[i] | ((unsigned int)dst[i] << 16);
            e.y = (unsigned int)__float_as_int(w[i]);
            er[k] = e;
            atomicAdd(&cnt[e.x >> 22], 1);   // bucket = dst>>6
        }
    }
    __syncthreads();
    for (int k = t; k < NBK; k += 256) {
        int c = cnt[k];
        bas[k] = c ? atomicAdd(&gcur[k], c) : 0;
    }
    for (int k = t; k < 1024; k += 256) sc[k] = (k < NBK) ? cnt[k] : 0;
    __syncthreads();
    for (int s = 1; s < 1024; s <<= 1) {
        int v0[4];
#pragma unroll
        for (int j = 0; j < 4; ++j) {
            int idx = t + j * 256;
            v0[j] = (idx >= s) ? sc[idx - s] : 0;
        }
        __syncthreads();
#pragma unroll
        for (int j = 0; j < 4; ++j) sc[t + j * 256] += v0[j];
        __syncthreads();
    }
#pragma unroll
    for (int k = 0; k < TILE / 256; ++k) {
        int i = base + k * 256 + t;
        if (i < NE) {
            uint2 e = er[k];
            int b = e.x >> 22;
            int r = atomicAdd(&rnk[b], 1);
            data[(sc[b] - cnt[b]) + r] = e;
        }
    }
    __syncthreads();
    int tot = NE - base; if (tot > TILE) tot = TILE;
    for (int idx = t; idx < tot; idx += 256) {
        uint2 e = data[idx];
        int b = e.x >> 22;
        int lb = sc[b] - cnt[b];
        tmp[(size_t)b * SCAP + bas[b] + (idx - lb)] = e;
    }
}

// block = bucket: two-pass counting sort; emits packed 4B CSR + (beg,end)
__global__ __launch_bounds__(256) void sort_kernel(const uint2* __restrict__ tmp,
                                                   const int* __restrict__ gcur,
                                                   unsigned int* __restrict__ csr,
                                                   int2* __restrict__ off2) {
    __shared__ int cnt[64], nb[64], pos[64];
    int b = blockIdx.x, t = threadIdx.x;
    int beg = b * SCAP, n = gcur[b];
    if (t < 64) cnt[t] = 0;
    __syncthreads();
    for (int i = t; i < n; i += 256) {
        uint2 e = tmp[beg + i];
        atomicAdd(&cnt[(e.x >> 16) & 63u], 1);
    }
    __syncthreads();
    if (t == 0) {
        int a = 0;
        for (int k = 0; k < 64; ++k) { nb[k] = a; pos[k] = a; a += cnt[k]; }
    }
    __syncthreads();
    for (int i = t; i < n; i += 256) {
        uint2 e = tmp[beg + i];
        int d = (int)((e.x >> 16) & 63u);
        unsigned int wh = (unsigned int)__half_as_ushort(
            __float2half_rn(__int_as_float((int)e.y)));
        int r = atomicAdd(&pos[d], 1);
        csr[beg + r] = (e.x & 0xffffu) | (wh << 16);
    }
    __syncthreads();
    if (t < 64) {
        int node = b * 64 + t;
        if (node < NN) {
            int2 oe;
            oe.x = beg + nb[t];
            oe.y = beg + nb[t] + cnt[t];
            off2[node] = oe;
        }
    }
}

// layer-0 MFMA GEMM: h = x32 @ W0^T + b0, f16 out. Block = 64 nodes (4 waves).
__global__ __launch_bounds__(256) void gemm0_mfma(const float* __restrict__ x32,
                                                  const _Float16* __restrict__ Wg,
                                                  const float* __restrict__ bl,
                                                  _Float16* __restrict__ h) {
    int t = threadIdx.x;
    int wave = t >> 6, lane = t & 63;
    int m = lane & 15, q = lane >> 4;
    int node0 = blockIdx.x * 64 + wave * 16;
    int arow = node0 + m; if (arow >= NN) arow = NN - 1;
    const float4* xr = (const float4*)(x32 + (size_t)arow * 64);
    float4 f0 = xr[2 * q], f1 = xr[2 * q + 1];
    float4 f2 = xr[8 + 2 * q], f3 = xr[8 + 2 * q + 1];
    half8 a0, a1;
    a0[0] = (_Float16)f0.x; a0[1] = (_Float16)f0.y; a0[2] = (_Float16)f0.z; a0[3] = (_Float16)f0.w;
    a0[4] = (_Float16)f1.x; a0[5] = (_Float16)f1.y; a0[6] = (_Float16)f1.z; a0[7] = (_Float16)f1.w;
    a1[0] = (_Float16)f2.x; a1[1] = (_Float16)f2.y; a1[2] = (_Float16)f2.z; a1[3] = (_Float16)f2.w;
    a1[4] = (_Float16)f3.x; a1[5] = (_Float16)f3.y; a1[6] = (_Float16)f3.z; a1[7] = (_Float16)f3.w;
    const half8* Wf = (const half8*)Wg;
    float4v acc[4];
#pragma unroll
    for (int nt = 0; nt < 4; ++nt) acc[nt] = (float4v){0.f, 0.f, 0.f, 0.f};
#pragma unroll
    for (int nt = 0; nt < 4; ++nt) {
        half8 b0 = Wf[(nt * 2 + 0) * 64 + lane];
        half8 b1 = Wf[(nt * 2 + 1) * 64 + lane];
        acc[nt] = __builtin_amdgcn_mfma_f32_16x16x32_f16(a0, b0, acc[nt], 0, 0, 0);
        acc[nt] = __builtin_amdgcn_mfma_f32_16x16x32_f16(a1, b1, acc[nt], 0, 0, 0);
    }
#pragma unroll
    for (int nt = 0; nt < 4; ++nt) {
        float bv = bl[nt * 16 + m];
#pragma unroll
        for (int r = 0; r < 4; ++r) {
            int node = node0 + q * 4 + r;
            if (node < NN)
                h[(size_t)node * 64 + nt * 16 + m] = (_Float16)(acc[nt][r] + bv);
        }
    }
}

// Fused pull + next-layer GEMM. Block = 16 nodes (4 waves x 4 nodes/wave).
// Reads hin (layer l), writes hout (layer l+1) -- DISTINCT buffers (ping-pong):
// the gather touches arbitrary src rows, so in-place update races across blocks.
__global__ __launch_bounds__(256) void pull_fused(const uint4* __restrict__ h16,
                                                  const unsigned int* __restrict__ csr,
                                                  const int2* __restrict__ off2,
                                                  float4* __restrict__ out,
                                                  const float4* __restrict__ x32,
                                                  const float* __restrict__ temp,
                                                  const _Float16* __restrict__ Wg,
                                                  const float* __restrict__ bl,
                                                  _Float16* __restrict__ hout,
                                                  int layer) {
    __shared__ _Float16 vsh[16 * 72];   // 2.3 KB, row stride 72 f16 = 144 B
    int t = threadIdx.x;
    int lane = t & 63;
    int slot = lane >> 4, g = (lane >> 3) & 1, sub = lane & 7;
    int node0 = blockIdx.x * 16;
    int nloc = (t >> 6) * 4 + slot;
    int node = node0 + nloc;
    bool tail = (node0 + 16 > NN);
    if (tail) {
        for (int k = t; k < 16 * 72; k += 256) vsh[k] = (_Float16)0.f;
        __syncthreads();
    }

    int nclamp = node < NN ? node : NN - 1;
    int2 oe = off2[nclamp];
    int deg = (node < NN) ? (oe.y - oe.x) : 0;
    int beg = oe.x;
    int dmax = deg;
    dmax = max(dmax, __shfl_xor(dmax, 16));
    dmax = max(dmax, __shfl_xor(dmax, 32));
    int sl = lane & 15;
    float acc[8];
#pragma unroll
    for (int k = 0; k < 8; ++k) acc[k] = 0.f;

    int chunks = (dmax + 15) >> 4;
    unsigned int e = (sl < deg) ? csr[beg + sl] : 0u;
    for (int c = 0; c < chunks; ++c) {
        int nidx = ((c + 1) << 4) + sl;
        unsigned int enext = (nidx < deg) ? csr[beg + nidx] : 0u;   // prefetch
#pragma unroll
        for (int j = 0; j < 8; ++j) {
            unsigned int ej = (unsigned int)__shfl((int)e, (slot << 4) + j * 2 + g);
            int s = (int)(ej & 0xffffu);
            __half wh = __ushort_as_half((unsigned short)(ej >> 16));
            uint4 hv = h16[(size_t)s * 8 + sub];
            const __half* hp = (const __half*)&hv;
            float wf = (float)wh;
#pragma unroll
            for (int k = 0; k < 8; ++k)
                acc[k] += (float)hp[k] * wf;   // v_fma_mix_f32
        }
        e = enext;
    }
#pragma unroll
    for (int k = 0; k < 8; ++k) acc[k] += __shfl_xor(acc[k], 8);

    if (g == 0 && node < NN) {   // lanes sl<8 hold feats sub*8..sub*8+7
        float tk = temp[layer + 1];
        float v[8];
#pragma unroll
        for (int k = 0; k < 8; ++k) v[k] = fmaxf(acc[k], 0.f);
        __half2 p[4];
#pragma unroll
        for (int k = 0; k < 4; ++k) p[k] = __floats2half2_rn(v[2 * k], v[2 * k + 1]);
        *(uint4*)&vsh[nloc * 72 + sub * 8] = *(const uint4*)p;
        int gi = node * 16 + sub * 2;
        float4 o0, o1;
        if (layer == 0) {
            float t0 = temp[0];
            float4 a = x32[gi], bq = x32[gi + 1];
            o0.x = a.x * t0;  o0.y = a.y * t0;  o0.z = a.z * t0;  o0.w = a.w * t0;
            o1.x = bq.x * t0; o1.y = bq.y * t0; o1.z = bq.z * t0; o1.w = bq.w * t0;
        } else {
            o0 = out[gi]; o1 = out[gi + 1];
        }
        o0.x += v[0] * tk; o0.y += v[1] * tk; o0.z += v[2] * tk; o0.w += v[3] * tk;
        o1.x += v[4] * tk; o1.y += v[5] * tk; o1.z += v[6] * tk; o1.w += v[7] * tk;
        out[gi]     = o0;
        out[gi + 1] = o1;
    }

    if (Wg != nullptr) {
        __syncthreads();
        int wave = t >> 6;                 // = output tile nt
        int m = lane & 15, q = lane >> 4;
        half8 a0 = *(const half8*)&vsh[m * 72 + q * 8];        // k = q*8+j
        half8 a1 = *(const half8*)&vsh[m * 72 + 32 + q * 8];   // k = 32+q*8+j
        const half8* Wf = (const half8*)Wg;
        half8 b0 = Wf[(wave * 2 + 0) * 64 + lane];
        half8 b1 = Wf[(wave * 2 + 1) * 64 + lane];
        float4v d = (float4v){0.f, 0.f, 0.f, 0.f};
        d = __builtin_amdgcn_mfma_f32_16x16x32_f16(a0, b0, d, 0, 0, 0);
        d = __builtin_amdgcn_mfma_f32_16x16x32_f16(a1, b1, d, 0, 0, 0);
        float bv = bl[wave * 16 + m];
#pragma unroll
        for (int r = 0; r < 4; ++r) {
            int n2 = node0 + q * 4 + r;
            if (n2 < NN)
                hout[(size_t)n2 * 64 + wave * 16 + m] = (_Float16)(d[r] + bv);
        }
    }
}

extern "C" void kernel_launch(void* const* d_in, const int* in_sizes, int n_in,
                              void* d_out, int out_size, void* d_ws, size_t ws_size,
                              hipStream_t stream) {
    const float* x    = (const float*)d_in[0];
    const float* w    = (const float*)d_in[1];
    const float* W    = (const float*)d_in[2];
    const float* b    = (const float*)d_in[3];
    const float* temp = (const float*)d_in[4];
    const int*   src  = (const int*)d_in[5];
    const int*   dst  = (const int*)d_in[6];
    float* out = (float*)d_out;

    // workspace layout (~42 MB)
    _Float16*     hA   = (_Float16*)d_ws;                          // NN*DD f16
    _Float16*     hB   = hA + (size_t)NN * DD;                     // NN*DD f16
    unsigned int* csr  = (unsigned int*)(hB + (size_t)NN * DD);    // NBK*SCAP u32
    uint2*        tmp  = (uint2*)(csr + (size_t)NBK * SCAP);       // NBK*SCAP uint2
    int*          gcur = (int*)(tmp + (size_t)NBK * SCAP);         // NBK
    int2*         off2 = (int2*)(gcur + NBK);                      // NN
    _Float16*     Wswz = (_Float16*)(off2 + NN);                   // 4*4096 f16

    // ---- CSR build + W pre-swizzle ----
    hipMemsetAsync(gcur, 0, (size_t)NBK * sizeof(int), stream);
    wswz_kernel<<<64, 256, 0, stream>>>(W, Wswz);
    fill_kernel<<<NTB, 256, 0, stream>>>(src, dst, w, gcur, tmp);
    sort_kernel<<<NBK, 256, 0, stream>>>(tmp, gcur, csr, off2);

    // ---- layer 0 GEMM from f32 x ----
    gemm0_mfma<<<NBK, 256, 0, stream>>>(x, Wswz, b, hA);

    // ---- fused pull + next-layer gemm, ping-pong h buffers ----
    const int PG = (NN + 15) / 16;
    _Float16* hin  = hA;
    _Float16* hout = hB;
    for (int l = 0; l < 4; ++l) {
        const _Float16* Wn = (l < 3) ? (Wswz + (size_t)(l + 1) * 4096) : nullptr;
        const float*    bn = (l < 3) ? (b + (size_t)(l + 1) * DD) : nullptr;
        pull_fused<<<PG, 256, 0, stream>>>(
            (const uint4*)hin, csr, off2, (float4*)out, (const float4*)x,
            temp, Wn, bn, hout, l);
        _Float16* sw = hin; hin = hout; hout = sw;
    }
}